// Round 1
// baseline (319.769 us; speedup 1.0000x reference)
//
#include <hip/hip_runtime.h>

// B=256, T=256, C=512, H=64. All inputs fp32; compute in f16 MFMA w/ fp32 acc.
// ws layout: q (65536x64 f16) | k | v  = 3 * 8,388,608 B = 25,165,824 B.

typedef _Float16 half8 __attribute__((ext_vector_type(8)));
typedef float floatx4 __attribute__((ext_vector_type(4)));

#define MFMA16(a, b, c) __builtin_amdgcn_mfma_f32_16x16x32_f16((a), (b), (c), 0, 0, 0)

__device__ inline half8 cvt8(float4 a, float4 b) {
  half8 r;
  r[0] = (_Float16)a.x; r[1] = (_Float16)a.y; r[2] = (_Float16)a.z; r[3] = (_Float16)a.w;
  r[4] = (_Float16)b.x; r[5] = (_Float16)b.y; r[6] = (_Float16)b.z; r[7] = (_Float16)b.w;
  return r;
}

// GEMM: out[m][n] = sum_k X[m][k] * W[k][n], M=65536 (128/block), K=512, N=64.
// NOUT=1: q = x*Wq.  NOUT=2: k = y*Wk and v = y*Wv (shares the y tile).
template <int NOUT>
__global__ __launch_bounds__(256) void proj_kernel(
    const float* __restrict__ X, const float* __restrict__ W0,
    const float* __restrict__ W1, _Float16* __restrict__ O0,
    _Float16* __restrict__ O1) {
  __shared__ _Float16 a_lds[128][40];        // 128 rows x 32 k, pad->40 (2-way ok)
  __shared__ _Float16 w_lds[NOUT][64][40];   // W^T: [n][k], pad->40

  const int tid = threadIdx.x;
  const int row0 = blockIdx.x * 128;
  const int wv = tid >> 6;
  const int lane = tid & 63;
  const int l15 = lane & 15, quad = lane >> 4;

  floatx4 acc[2][4 * NOUT];
#pragma unroll
  for (int i = 0; i < 2; i++)
#pragma unroll
    for (int j = 0; j < 4 * NOUT; j++) acc[i][j] = (floatx4)0.f;

  const int arow = tid >> 1;            // 0..127
  const int ahalf = (tid & 1) * 16;     // 0 or 16 (k-cols)
  const int wkk = tid >> 3;             // 0..31 (k row of W)
  const int wn0 = (tid & 7) * 8;        // 0..56 (n col of W)

  for (int k0 = 0; k0 < 512; k0 += 32) {
    // ---- stage A tile (128 x 32), fp32 -> f16 ----
    {
      const float4* s4 = (const float4*)(X + (size_t)(row0 + arow) * 512 + k0 + ahalf);
      float4 f0 = s4[0], f1 = s4[1], f2 = s4[2], f3 = s4[3];
      *(half8*)&a_lds[arow][ahalf]     = cvt8(f0, f1);
      *(half8*)&a_lds[arow][ahalf + 8] = cvt8(f2, f3);
    }
    // ---- stage W^T tile(s) (64 n x 32 k), transposed scalar writes ----
#pragma unroll
    for (int wi = 0; wi < NOUT; wi++) {
      const float* wsrc = (wi ? W1 : W0) + (size_t)(k0 + wkk) * 64 + wn0;
      float4 g0 = ((const float4*)wsrc)[0];
      float4 g1 = ((const float4*)wsrc)[1];
      w_lds[wi][wn0 + 0][wkk] = (_Float16)g0.x;
      w_lds[wi][wn0 + 1][wkk] = (_Float16)g0.y;
      w_lds[wi][wn0 + 2][wkk] = (_Float16)g0.z;
      w_lds[wi][wn0 + 3][wkk] = (_Float16)g0.w;
      w_lds[wi][wn0 + 4][wkk] = (_Float16)g1.x;
      w_lds[wi][wn0 + 5][wkk] = (_Float16)g1.y;
      w_lds[wi][wn0 + 6][wkk] = (_Float16)g1.z;
      w_lds[wi][wn0 + 7][wkk] = (_Float16)g1.w;
    }
    __syncthreads();
    // ---- MFMA: each wave does 32 rows x (64*NOUT) cols ----
    half8 af0 = *(const half8*)&a_lds[wv * 32 + l15][quad * 8];
    half8 af1 = *(const half8*)&a_lds[wv * 32 + 16 + l15][quad * 8];
#pragma unroll
    for (int wi = 0; wi < NOUT; wi++)
#pragma unroll
      for (int j = 0; j < 4; j++) {
        half8 bf = *(const half8*)&w_lds[wi][j * 16 + l15][quad * 8];
        acc[0][wi * 4 + j] = MFMA16(af0, bf, acc[0][wi * 4 + j]);
        acc[1][wi * 4 + j] = MFMA16(af1, bf, acc[1][wi * 4 + j]);
      }
    __syncthreads();
  }
  // ---- epilogue: C/D layout col=l15, row=quad*4+r ----
#pragma unroll
  for (int i = 0; i < 2; i++)
#pragma unroll
    for (int wi = 0; wi < NOUT; wi++) {
      _Float16* O = wi ? O1 : O0;
#pragma unroll
      for (int j = 0; j < 4; j++)
#pragma unroll
        for (int r = 0; r < 4; r++) {
          int grow = row0 + wv * 32 + i * 16 + quad * 4 + r;
          O[(size_t)grow * 64 + j * 16 + l15] = (_Float16)acc[i][wi * 4 + j][r];
        }
    }
}

// Flash attention, causal. Grid (qt=4, b=256); block 256 = 4 waves x 16 q-rows.
__global__ __launch_bounds__(256) void attn_kernel(
    const _Float16* __restrict__ Qw, const _Float16* __restrict__ Kw,
    const _Float16* __restrict__ Vw, float* __restrict__ Out) {
  __shared__ _Float16 k_lds[64][72];       // [s][h], pad 72 (2-way on reads)
  __shared__ _Float16 vt_lds[64][72];      // [h][s] (V transposed)
  __shared__ _Float16 p_lds[4][16][72];    // per-wave P round-trip

  const int qt = blockIdx.x, bb = blockIdx.y;
  const int tid = threadIdx.x;
  const int wv = tid >> 6;
  const int lane = tid & 63;
  const int l15 = lane & 15, quad = lane >> 4;
  const float SCALE = 0.125f * 1.4426950408889634f;  // (1/sqrt(64)) * log2(e)
  const float NEG = -3.0e38f;

  // Q fragments live in registers for the whole kernel (A layout: m=l15, k=quad*8+j)
  const size_t qoff = ((size_t)bb * 256 + qt * 64 + wv * 16 + l15) * 64 + quad * 8;
  half8 qf0 = *(const half8*)(Qw + qoff);
  half8 qf1 = *(const half8*)(Qw + qoff + 32);

  floatx4 o[4];
#pragma unroll
  for (int t = 0; t < 4; t++) o[t] = (floatx4)0.f;
  float mrow[4], lrow[4];
#pragma unroll
  for (int r = 0; r < 4; r++) { mrow[r] = NEG; lrow[r] = 0.f; }

  const int srow = tid >> 2;          // 0..63
  const int sc = (tid & 3) * 16;      // 0,16,32,48

  for (int j = 0; j <= qt; j++) {
    __syncthreads();  // protect k_lds/vt_lds from previous iteration's readers
    {
      const size_t base = ((size_t)bb * 256 + j * 64 + srow) * 64 + sc;
      const half8* ksrc = (const half8*)(Kw + base);
      half8 ka = ksrc[0], kb = ksrc[1];
      *(half8*)&k_lds[srow][sc]     = ka;
      *(half8*)&k_lds[srow][sc + 8] = kb;
      const half8* vsrc = (const half8*)(Vw + base);
      half8 va = vsrc[0], vb = vsrc[1];
#pragma unroll
      for (int e = 0; e < 8; e++) vt_lds[sc + e][srow] = va[e];
#pragma unroll
      for (int e = 0; e < 8; e++) vt_lds[sc + 8 + e][srow] = vb[e];
    }
    __syncthreads();

    // S = Q K^T : 16 q-rows x 64 s-cols per wave
    floatx4 sacc[4];
#pragma unroll
    for (int t = 0; t < 4; t++) sacc[t] = (floatx4)0.f;
#pragma unroll
    for (int t = 0; t < 4; t++) {
      half8 b0 = *(const half8*)&k_lds[t * 16 + l15][quad * 8];
      sacc[t] = MFMA16(qf0, b0, sacc[t]);
      half8 b1 = *(const half8*)&k_lds[t * 16 + l15][32 + quad * 8];
      sacc[t] = MFMA16(qf1, b1, sacc[t]);
    }

    // scale + causal mask (C/D layout: col = t*16+l15, row = quad*4+r)
    float y[4][4];
#pragma unroll
    for (int t = 0; t < 4; t++)
#pragma unroll
      for (int r = 0; r < 4; r++) y[t][r] = sacc[t][r] * SCALE;
    if (j == qt) {
#pragma unroll
      for (int t = 0; t < 4; t++)
#pragma unroll
        for (int r = 0; r < 4; r++)
          if (t * 16 + l15 > wv * 16 + quad * 4 + r) y[t][r] = NEG;
    }

    // online softmax per q-row (reduce across the quad's 16 lanes)
#pragma unroll
    for (int r = 0; r < 4; r++) {
      float mx = fmaxf(fmaxf(y[0][r], y[1][r]), fmaxf(y[2][r], y[3][r]));
#pragma unroll
      for (int off = 1; off < 16; off <<= 1) mx = fmaxf(mx, __shfl_xor(mx, off, 64));
      float mnew = fmaxf(mrow[r], mx);
      float al = exp2f(mrow[r] - mnew);
      mrow[r] = mnew;
      float rs = 0.f;
#pragma unroll
      for (int t = 0; t < 4; t++) {
        float p = exp2f(y[t][r] - mnew);
        y[t][r] = p;
        rs += p;
      }
#pragma unroll
      for (int off = 1; off < 16; off <<= 1) rs += __shfl_xor(rs, off, 64);
      lrow[r] = lrow[r] * al + rs;
      o[0][r] *= al; o[1][r] *= al; o[2][r] *= al; o[3][r] *= al;
    }

    // P: C/D layout -> LDS -> A layout (per-wave private region)
#pragma unroll
    for (int t = 0; t < 4; t++)
#pragma unroll
      for (int r = 0; r < 4; r++)
        p_lds[wv][quad * 4 + r][t * 16 + l15] = (_Float16)y[t][r];
    __syncthreads();

    // O += P V
#pragma unroll
    for (int ss = 0; ss < 2; ss++) {
      half8 pa = *(const half8*)&p_lds[wv][l15][ss * 32 + quad * 8];
#pragma unroll
      for (int th = 0; th < 4; th++) {
        half8 vb = *(const half8*)&vt_lds[th * 16 + l15][ss * 32 + quad * 8];
        o[th] = MFMA16(pa, vb, o[th]);
      }
    }
  }

  // normalize + store fp32
#pragma unroll
  for (int th = 0; th < 4; th++)
#pragma unroll
    for (int r = 0; r < 4; r++) {
      int grow = qt * 64 + wv * 16 + quad * 4 + r;
      Out[((size_t)bb * 256 + grow) * 64 + th * 16 + l15] = o[th][r] / lrow[r];
    }
}

extern "C" void kernel_launch(void* const* d_in, const int* in_sizes, int n_in,
                              void* d_out, int out_size, void* d_ws, size_t ws_size,
                              hipStream_t stream) {
  const float* x  = (const float*)d_in[0];
  const float* y  = (const float*)d_in[1];
  const float* Wq = (const float*)d_in[2];
  const float* Wk = (const float*)d_in[3];
  const float* Wv = (const float*)d_in[4];
  float* out = (float*)d_out;

  _Float16* qw = (_Float16*)d_ws;
  _Float16* kw = qw + (size_t)65536 * 64;
  _Float16* vw = kw + (size_t)65536 * 64;

  proj_kernel<1><<<512, 256, 0, stream>>>(x, Wq, nullptr, qw, nullptr);
  proj_kernel<2><<<512, 256, 0, stream>>>(y, Wk, Wv, kw, vw);
  attn_kernel<<<dim3(4, 256), 256, 0, stream>>>(qw, kw, vw, out);
}